// Round 4
// baseline (531.355 us; speedup 1.0000x reference)
//
#include <hip/hip_runtime.h>
#include <math.h>

#define EPSV 1e-4f
#define NG 8
#define LL 64
#define NB 32
#define CC 512
#define HWS 3136
#define MTOT (NB * HWS)
#define NPI 19
#define NTILES 49
#define NPW 3  // k_whiten parts: 50KB LDS/block -> 3 blocks/CU, 768 blocks = 3/CU exact

// ---------------------------------------------------------------------------
// Pure-DPP wave reductions (no LDS-pipe round trips; critical for k_power
// where 1 wave/CU exposes every cross-lane latency).
// row_shr 1/2/4/8 -> lane15 of each 16-row holds row sum; row_bcast15 (rows
// 1,3) + row_bcast31 (rows 2,3) -> lane 63 holds full sum; readlane -> SGPR
// broadcast to all lanes.
// ---------------------------------------------------------------------------
template <int CTRL, int RMASK, bool BC>
__device__ __forceinline__ float dpp_fadd(float v) {
  int x = __builtin_amdgcn_update_dpp(0, __float_as_int(v), CTRL, RMASK, 0xF, BC);
  return v + __int_as_float(x);
}

__device__ __forceinline__ float wave_allsum(float v) {
  v = dpp_fadd<0x111, 0xF, true>(v);   // row_shr:1
  v = dpp_fadd<0x112, 0xF, true>(v);   // row_shr:2
  v = dpp_fadd<0x114, 0xF, true>(v);   // row_shr:4
  v = dpp_fadd<0x118, 0xF, true>(v);   // row_shr:8
  v = dpp_fadd<0x142, 0xa, false>(v);  // row_bcast:15 -> rows 1,3
  v = dpp_fadd<0x143, 0xc, false>(v);  // row_bcast:31 -> rows 2,3
  return __int_as_float(__builtin_amdgcn_readlane(__float_as_int(v), 63));
}

// sum within each 16-lane row; valid in lane 15 of each row
__device__ __forceinline__ float row16_sum(float v) {
  v = dpp_fadd<0x111, 0xF, true>(v);
  v = dpp_fadd<0x112, 0xF, true>(v);
  v = dpp_fadd<0x114, 0xF, true>(v);
  v = dpp_fadd<0x118, 0xF, true>(v);
  return v;
}

// ---------------------------------------------------------------------------
// Kernel A: channel sums + raw second moments. ONE WAVE per (g,n,part) tile
// stream, 8x8 per-thread blocking: per m-quad 16 ds_read_b128 feed 256 MACs
// (1 B/MAC LDS traffic, half of the 4x4 version -> ~63us LDS floor).
// xs layout [ch][m] with 16B-slot XOR swizzle (slot = m4 ^ (ch>>3)); without
// it the 8 ty-groups of an A-fragment read alias 4 banks (8-way conflict).
// ---------------------------------------------------------------------------
__global__ __launch_bounds__(64, 2) void k_moments(const float* __restrict__ x,
                                                   float* __restrict__ prods,
                                                   float* __restrict__ sums,
                                                   int nparts) {
  const int g = blockIdx.x, n = blockIdx.y, h = blockIdx.z;
  const int l = threadIdx.x;          // 0..63
  const int c = l >> 4, m4w = l & 15; // staging map
  const int ty = l >> 3, tx = l & 7;  // compute map (8x8 grid of 8x8 tiles)
  __shared__ float xs[64 * 64];
  const float* xp = x + ((size_t)(n * CC + g * LL)) * HWS;

  float acc[8][8];
#pragma unroll
  for (int a = 0; a < 8; ++a)
#pragma unroll
    for (int b = 0; b < 8; ++b) acc[a][b] = 0.f;
  float csum[16];
#pragma unroll
  for (int r = 0; r < 16; ++r) csum[r] = 0.f;

  const int tpp = (NTILES + nparts - 1) / nparts;
  const int t0 = h * tpp;
  const int t1 = (t0 + tpp < NTILES) ? (t0 + tpp) : NTILES;

  for (int t = t0; t < t1; ++t) {
    const int hw0 = t * 64;
    __syncthreads();
#pragma unroll
    for (int r = 0; r < 16; ++r) {
      const int ch = r * 4 + c;
      float4 gv = *(const float4*)&xp[ch * HWS + hw0 + m4w * 4];
      csum[r] += (gv.x + gv.y) + (gv.z + gv.w);
      const int slot = m4w ^ (ch >> 3);
      *(float4*)&xs[ch * 64 + slot * 4] = gv;
    }
    __syncthreads();
#pragma unroll 2
    for (int m4 = 0; m4 < 16; ++m4) {
      float4 av[8], bv[8];
#pragma unroll
      for (int ii = 0; ii < 8; ++ii)
        av[ii] = *(const float4*)&xs[(ty * 8 + ii) * 64 + ((m4 ^ ty) * 4)];
#pragma unroll
      for (int jj = 0; jj < 8; ++jj)
        bv[jj] = *(const float4*)&xs[(tx * 8 + jj) * 64 + ((m4 ^ tx) * 4)];
#pragma unroll
      for (int ii = 0; ii < 8; ++ii)
#pragma unroll
        for (int jj = 0; jj < 8; ++jj) {
          acc[ii][jj] += av[ii].x * bv[jj].x;
          acc[ii][jj] += av[ii].y * bv[jj].y;
          acc[ii][jj] += av[ii].z * bv[jj].z;
          acc[ii][jj] += av[ii].w * bv[jj].w;
        }
    }
  }

  const int p = n * nparts + h;
  float* pp = prods + ((size_t)(g * NB * nparts + p)) * 4096;
#pragma unroll
  for (int ii = 0; ii < 8; ++ii) {
    *(float4*)&pp[(ty * 8 + ii) * 64 + tx * 8] =
        make_float4(acc[ii][0], acc[ii][1], acc[ii][2], acc[ii][3]);
    *(float4*)&pp[(ty * 8 + ii) * 64 + tx * 8 + 4] =
        make_float4(acc[ii][4], acc[ii][5], acc[ii][6], acc[ii][7]);
  }
#pragma unroll
  for (int r = 0; r < 16; ++r) {
    float s = row16_sum(csum[r]); // sum over the 16 m4w lanes of group c
    if (m4w == 15) sums[((size_t)(g * NB * nparts + p)) * 64 + r * 4 + c] = s;
  }
}

// ---------------------------------------------------------------------------
// Kernel B1: mu[g*64+c] = sum over partials / M.  Tiny.
// ---------------------------------------------------------------------------
__global__ __launch_bounds__(64) void k_mu(const float* __restrict__ sums,
                                           float* __restrict__ mu, int P) {
  const int g = blockIdx.x;
  const int tid = threadIdx.x;
  const float* sp = sums + (size_t)g * P * 64 + tid;
  float s0 = 0.f, s1 = 0.f, s2 = 0.f, s3 = 0.f;
  int p = 0;
  for (; p + 4 <= P; p += 4) {
    s0 += sp[(size_t)(p + 0) * 64];
    s1 += sp[(size_t)(p + 1) * 64];
    s2 += sp[(size_t)(p + 2) * 64];
    s3 += sp[(size_t)(p + 3) * 64];
  }
  for (; p < P; ++p) s0 += sp[(size_t)p * 64];
  mu[g * 64 + tid] = ((s0 + s1) + (s2 + s3)) / (float)MTOT;
}

// ---------------------------------------------------------------------------
// Kernel B2: cov = S/M - mu_i mu_j + eps*I.
// ---------------------------------------------------------------------------
__global__ __launch_bounds__(256) void k_cov(const float* __restrict__ prods,
                                             const float* __restrict__ mu,
                                             float* __restrict__ cov, int P) {
  const int g = blockIdx.x;
  const int e = blockIdx.y * 256 + threadIdx.x;
  const int i = e >> 6, j = e & 63;
  const float* pp = prods + (size_t)g * P * 4096 + e;
  float s0 = 0.f, s1 = 0.f, s2 = 0.f, s3 = 0.f;
  int p = 0;
  for (; p + 4 <= P; p += 4) {
    s0 += pp[(size_t)(p + 0) * 4096];
    s1 += pp[(size_t)(p + 1) * 4096];
    s2 += pp[(size_t)(p + 2) * 4096];
    s3 += pp[(size_t)(p + 3) * 4096];
  }
  for (; p < P; ++p) s0 += pp[(size_t)p * 4096];
  const float s = (s0 + s1) + (s2 + s3);
  const float cv =
      s / (float)MTOT - mu[g * 64 + i] * mu[g * 64 + j] + (i == j ? EPSV : 0.f);
  cov[(size_t)g * 4096 + e] = cv;
}

// ---------------------------------------------------------------------------
// Kernel C: sequential power iteration + deflation. One wave per group.
// All wave reductions are pure-DPP + readlane (no ds_swizzle/ds_bpermute).
// ---------------------------------------------------------------------------
__device__ __forceinline__ float dot64(const float* Arow, const float* v_sh) {
  float d0 = 0.f, d1 = 0.f, d2 = 0.f, d3 = 0.f;
#pragma unroll
  for (int c4 = 0; c4 < 16; ++c4) {
    float4 vv = ((const float4*)v_sh)[c4];
    d0 += Arow[c4 * 4 + 0] * vv.x;
    d1 += Arow[c4 * 4 + 1] * vv.y;
    d2 += Arow[c4 * 4 + 2] * vv.z;
    d3 += Arow[c4 * 4 + 3] * vv.w;
  }
  return (d0 + d1) + (d2 + d3);
}

__global__ __launch_bounds__(64, 1) void k_power(const float* __restrict__ v_init,
                                                 const float* __restrict__ cov,
                                                 float* __restrict__ sub) {
  const int g = blockIdx.x;
  const int r = threadIdx.x;
  __shared__ __align__(16) float v_sh[64];
  float Arow[64], Srow[64];
  const float4* crow = (const float4*)(cov + (size_t)g * 4096 + r * 64);
#pragma unroll
  for (int c4 = 0; c4 < 16; ++c4) {
    float4 cv = crow[c4];
    Arow[c4 * 4 + 0] = cv.x;
    Arow[c4 * 4 + 1] = cv.y;
    Arow[c4 * 4 + 2] = cv.z;
    Arow[c4 * 4 + 3] = cv.w;
    Srow[c4 * 4 + 0] = 0.f;
    Srow[c4 * 4 + 1] = 0.f;
    Srow[c4 * 4 + 2] = 0.f;
    Srow[c4 * 4 + 3] = 0.f;
  }

  float lam_prev = 0.f;
  for (int j = 0; j < 64; ++j) {
    // v = l2n(v_init[j])
    float v0 = v_init[((size_t)g * 64 + j) * 64 + r];
    float ss = wave_allsum(v0 * v0);
    float vr = v0 / (sqrtf(ss) + 1e-12f);
    __syncthreads();
    v_sh[r] = vr;
    __syncthreads();

    for (int it = 0; it < NPI; ++it) {
      float w = dot64(Arow, v_sh);
      float s2 = wave_allsum(w * w);
      vr = w / (sqrtf(s2) + 1e-12f);
      __syncthreads();
      v_sh[r] = vr;
      __syncthreads();
    }

    const float Avr = dot64(Arow, v_sh); // (A v)[r]
    const float num = wave_allsum(vr * Avr);
    const float den = wave_allsum(vr * vr);
    const float lam = num / den; // wave-uniform

    if (j > 0 && (lam_prev < lam || lam < EPSV)) break;

    const float sc = 1.f / sqrtf(lam);
    const float svr = sc * vr;
#pragma unroll
    for (int c4 = 0; c4 < 16; ++c4) {
      float4 vv = ((const float4*)v_sh)[c4];
      Srow[c4 * 4 + 0] += svr * vv.x;
      Srow[c4 * 4 + 1] += svr * vv.y;
      Srow[c4 * 4 + 2] += svr * vv.z;
      Srow[c4 * 4 + 3] += svr * vv.w;
      Arow[c4 * 4 + 0] -= Avr * vv.x; // A -= outer(Av, v)  (== A - A@vv^T)
      Arow[c4 * 4 + 1] -= Avr * vv.y;
      Arow[c4 * 4 + 2] -= Avr * vv.z;
      Arow[c4 * 4 + 3] -= Avr * vv.w;
    }
    lam_prev = lam;
  }

  float4* srow = (float4*)(sub + (size_t)g * 4096 + r * 64);
#pragma unroll
  for (int c4 = 0; c4 < 16; ++c4)
    srow[c4] = make_float4(Srow[c4 * 4 + 0], Srow[c4 * 4 + 1], Srow[c4 * 4 + 2],
                           Srow[c4 * 4 + 3]);
}

// ---------------------------------------------------------------------------
// Kernel D: y = (S @ (x - mu)) * weight + bias, refactored as
// y = (S@x - smu) * weight + bias with smu = S@mu (hoisted, exact algebra).
// 2 waves per block, each wave owns one 64x64 tile stream (own xs buffer),
// sharing the transposed SS. 8x8 per-thread blocking: per j, 4 ds_read_b128
// feed 64 MACs (1 B/MAC). xs linear [64][64] is conflict-free for this read
// pattern (stride-32B lanes = 2-way). SS[64][68] pad keeps b128 reads
// aligned and 2-way.
// ---------------------------------------------------------------------------
__global__ __launch_bounds__(128, 2) void k_whiten(const float* __restrict__ x,
                                                   const float* __restrict__ weight,
                                                   const float* __restrict__ bias,
                                                   const float* __restrict__ mu,
                                                   const float* __restrict__ sub,
                                                   float* __restrict__ out,
                                                   int nparts) {
  const int g = blockIdx.x, n = blockIdx.y, h = blockIdx.z;
  const int tid = threadIdx.x;
  const int w = tid >> 6, l = tid & 63;
  const int c = l >> 4, m4w = l & 15; // staging map
  const int ty = l >> 3, tx = l & 7;  // compute map
  __shared__ float SS[64][68]; // SS[j][i] = S[i][j]
  __shared__ float xsb[2][64 * 64];
  __shared__ float mu_sh[64];
  float* xs = xsb[w];

  const float* sp = sub + (size_t)g * 4096;
  for (int i = w * 32; i < w * 32 + 32; ++i) SS[l][i] = sp[i * 64 + l];
  if (tid < 64) mu_sh[tid] = mu[g * 64 + tid];

  float wgt[8], bs[8];
#pragma unroll
  for (int ii = 0; ii < 8; ++ii) {
    const int cch = g * LL + ty * 8 + ii;
    wgt[ii] = weight[cch];
    bs[ii] = bias[cch];
  }
  __syncthreads();

  // smu[ii] = sum_j S[ty*8+ii][j] * mu[j]  (once per block)
  float smu[8];
#pragma unroll
  for (int ii = 0; ii < 8; ++ii) smu[ii] = 0.f;
#pragma unroll 4
  for (int j = 0; j < 64; ++j) {
    const float mj = mu_sh[j];
    float4 s0 = *(const float4*)&SS[j][ty * 8];
    float4 s1 = *(const float4*)&SS[j][ty * 8 + 4];
    smu[0] += s0.x * mj; smu[1] += s0.y * mj;
    smu[2] += s0.z * mj; smu[3] += s0.w * mj;
    smu[4] += s1.x * mj; smu[5] += s1.y * mj;
    smu[6] += s1.z * mj; smu[7] += s1.w * mj;
  }

  const float* xp = x + ((size_t)(n * CC + g * LL)) * HWS;
  float* yp = out + ((size_t)(n * CC + g * LL)) * HWS;
  const int tpp = (NTILES + nparts - 1) / nparts;
  const int t0 = h * tpp;
  const int t1 = (t0 + tpp < NTILES) ? (t0 + tpp) : NTILES;
  const int nt = t1 - t0;
  const int rounds = (nt + 1) >> 1; // both waves execute all barriers

  for (int rr = 0; rr < rounds; ++rr) {
    const int t = t0 + rr * 2 + w;
    const bool act = t < t1;
    const int hw0 = t * 64;
    __syncthreads();
    if (act) {
#pragma unroll
      for (int r = 0; r < 16; ++r) {
        const int ch = r * 4 + c;
        float4 gv = *(const float4*)&xp[ch * HWS + hw0 + m4w * 4];
        *(float4*)&xs[ch * 64 + m4w * 4] = gv; // raw x; mu handled via smu
      }
    }
    __syncthreads();
    if (!act) continue;

    float acc[8][8];
#pragma unroll
    for (int ii = 0; ii < 8; ++ii)
#pragma unroll
      for (int jj = 0; jj < 8; ++jj) acc[ii][jj] = 0.f;

#pragma unroll 4
    for (int j = 0; j < 64; ++j) {
      float4 s0 = *(const float4*)&SS[j][ty * 8];
      float4 s1 = *(const float4*)&SS[j][ty * 8 + 4];
      float4 x0 = *(const float4*)&xs[j * 64 + tx * 8];
      float4 x1 = *(const float4*)&xs[j * 64 + tx * 8 + 4];
      float sv[8] = {s0.x, s0.y, s0.z, s0.w, s1.x, s1.y, s1.z, s1.w};
      float xv[8] = {x0.x, x0.y, x0.z, x0.w, x1.x, x1.y, x1.z, x1.w};
#pragma unroll
      for (int ii = 0; ii < 8; ++ii)
#pragma unroll
        for (int jj = 0; jj < 8; ++jj) acc[ii][jj] += sv[ii] * xv[jj];
    }

#pragma unroll
    for (int ii = 0; ii < 8; ++ii) {
      float4 o0, o1;
      o0.x = (acc[ii][0] - smu[ii]) * wgt[ii] + bs[ii];
      o0.y = (acc[ii][1] - smu[ii]) * wgt[ii] + bs[ii];
      o0.z = (acc[ii][2] - smu[ii]) * wgt[ii] + bs[ii];
      o0.w = (acc[ii][3] - smu[ii]) * wgt[ii] + bs[ii];
      o1.x = (acc[ii][4] - smu[ii]) * wgt[ii] + bs[ii];
      o1.y = (acc[ii][5] - smu[ii]) * wgt[ii] + bs[ii];
      o1.z = (acc[ii][6] - smu[ii]) * wgt[ii] + bs[ii];
      o1.w = (acc[ii][7] - smu[ii]) * wgt[ii] + bs[ii];
      *(float4*)&yp[(ty * 8 + ii) * HWS + hw0 + tx * 8] = o0;
      *(float4*)&yp[(ty * 8 + ii) * HWS + hw0 + tx * 8 + 4] = o1;
    }
  }
}

extern "C" void kernel_launch(void* const* d_in, const int* in_sizes, int n_in,
                              void* d_out, int out_size, void* d_ws, size_t ws_size,
                              hipStream_t stream) {
  const float* x = (const float*)d_in[0];
  const float* v_init = (const float*)d_in[1];
  const float* weight = (const float*)d_in[2];
  const float* bias = (const float*)d_in[3];
  float* out = (float*)d_out;
  float* ws = (float*)d_ws;

  // ws budget: prods G*P*4096 + sums G*P*64 + mu 512 + cov G*4096 + sub G*4096
  const size_t fixed = (size_t)512 + (size_t)2 * NG * 4096;
  auto need = [&](int np) {
    return ((size_t)NG * NB * np * (4096 + 64) + fixed) * sizeof(float);
  };
  int nparts = 7; // 49 tiles = 7x7 -> 1792 one-wave blocks = 7 waves/CU
  if (ws_size < need(nparts)) nparts = 4;
  if (ws_size < need(nparts)) nparts = 2;
  if (ws_size < need(nparts)) nparts = 1;

  const int P = NB * nparts;
  float* prods = ws;
  float* sums = prods + (size_t)NG * P * 4096;
  float* mu = sums + (size_t)NG * P * 64;
  float* cov = mu + 512;
  float* sub = cov + (size_t)NG * 4096;

  k_moments<<<dim3(NG, NB, nparts), 64, 0, stream>>>(x, prods, sums, nparts);
  k_mu<<<NG, 64, 0, stream>>>(sums, mu, P);
  k_cov<<<dim3(NG, 16), 256, 0, stream>>>(prods, mu, cov, P);
  k_power<<<NG, 64, 0, stream>>>(v_init, cov, sub);
  k_whiten<<<dim3(NG, NB, NPW), 128, 0, stream>>>(x, weight, bias, mu, sub, out, NPW);
}